// Round 2
// baseline (3687.093 us; speedup 1.0000x reference)
//
#include <hip/hip_runtime.h>
#include <stdint.h>
#include <math.h>

// Autoregressive LSTM controller.
// B=4096, EMB=128, HID=512, OUT=64, STEPS=20.
// Key ideas this round:
//  - E_proj[64][2048] = embedding @ W_ih.T + b_ih + b_hh precomputed once
//    (only 64 distinct tokens) -> per-step input GEMM becomes a gather.
//  - Per step: fused fp32 GEMM (h @ W_hh.T) + LSTM elementwise (gates never
//    materialized in HBM), then a 1-wave-per-row logits/softmax/sample kernel.
//  - Sampling replicates JAX threefry2x32 with jax_threefry_partitionable=True
//    semantics (split: counts (0,t); bits: out0^out1 of counts (0, idx)).
//    If absmax fails ~1e-2..1 with correct magnitude ordering, flip to the
//    original (non-partitionable) threefry path next round.

#define B_SZ  4096
#define EMB   128
#define HID   512
#define NOUT  64
#define STEPS 20
#define G4    2048   // 4*HID

// ---------------- threefry2x32 ----------------
__device__ __forceinline__ void tf2x32(uint32_t k0, uint32_t k1,
                                       uint32_t x0, uint32_t x1,
                                       uint32_t& o0, uint32_t& o1) {
  const uint32_t ks2 = k0 ^ k1 ^ 0x1BD11BDAu;
#define TFR(r) { x0 += x1; x1 = (x1 << (r)) | (x1 >> (32 - (r))); x1 ^= x0; }
  x0 += k0; x1 += k1;
  TFR(13) TFR(15) TFR(26) TFR(6)
  x0 += k1;  x1 += ks2 + 1u;
  TFR(17) TFR(29) TFR(16) TFR(24)
  x0 += ks2; x1 += k0 + 2u;
  TFR(13) TFR(15) TFR(26) TFR(6)
  x0 += k0;  x1 += k1 + 3u;
  TFR(17) TFR(29) TFR(16) TFR(24)
  x0 += k1;  x1 += ks2 + 4u;
  TFR(13) TFR(15) TFR(26) TFR(6)
  x0 += ks2; x1 += k0 + 5u;
#undef TFR
  o0 = x0; o1 = x1;
}

// ---------------- E_proj = emb @ W_ih.T + b_ih + b_hh ----------------
__global__ __launch_bounds__(256) void eproj_kernel(
    const float* __restrict__ emb, const float* __restrict__ W_ih,
    const float* __restrict__ b_ih, const float* __restrict__ b_hh,
    float* __restrict__ E) {
  const int t = blockIdx.x;  // token 0..63
  __shared__ float es[EMB];
  for (int k = threadIdx.x; k < EMB; k += blockDim.x) es[k] = emb[t * EMB + k];
  __syncthreads();
  for (int j = threadIdx.x; j < G4; j += blockDim.x) {
    const float* w = W_ih + (size_t)j * EMB;
    float acc = 0.f;
#pragma unroll 8
    for (int k = 0; k < EMB; k += 4) {
      float4 wv = *(const float4*)(w + k);
      acc += wv.x * es[k] + wv.y * es[k + 1] + wv.z * es[k + 2] + wv.w * es[k + 3];
    }
    E[(size_t)t * G4 + j] = acc + b_ih[j] + b_hh[j];
  }
}

// ---------------- fused gates GEMM + LSTM cell ----------------
// grid (8 n-tiles, 64 m-tiles), 256 threads.
// Block computes 64 rows x 64 cols of each gate section (i,f,g,o).
__global__ __launch_bounds__(256) void lstm_step_kernel(
    const float* __restrict__ h_in,  // [B][HID]
    float*       __restrict__ c,     // [B][HID] in-place
    float*       __restrict__ h_out, // [B][HID]
    const float* __restrict__ W_hh,  // [2048][512]
    const float* __restrict__ E,     // [64][2048]
    const int*   __restrict__ tok)   // [B]
{
  __shared__ float As[16][68];
  __shared__ float Bs[4][16][68];

  const int tid = threadIdx.x;
  const int tx = tid & 15, ty = tid >> 4;
  const int nb = blockIdx.x, mb = blockIdx.y;

  float acc[4][4][4];
#pragma unroll
  for (int s = 0; s < 4; ++s)
#pragma unroll
    for (int i = 0; i < 4; ++i)
#pragma unroll
      for (int j = 0; j < 4; ++j) acc[s][i][j] = 0.f;

  // A staging: thread loads float4 of h[mb*64+rowA][ka..ka+3]
  const int rowA = tid >> 2;
  const int ka = (tid & 3) << 2;
  const float* aptr = h_in + (size_t)(mb * 64 + rowA) * HID + ka;

  // B staging: 4 reps; rep r handles l = tid + 256*r
  const float* bptr[4];
  int bs_s[4], bs_jj[4], bs_kc[4];
#pragma unroll
  for (int rep = 0; rep < 4; ++rep) {
    int l = tid + 256 * rep;
    int jl = l >> 2;
    bs_s[rep] = jl >> 6;
    bs_jj[rep] = jl & 63;
    bs_kc[rep] = (l & 3) << 2;
    bptr[rep] = W_hh + (size_t)(bs_s[rep] * 512 + nb * 64 + bs_jj[rep]) * HID + bs_kc[rep];
  }

  float4 ra = *(const float4*)aptr;
  float4 rb[4];
#pragma unroll
  for (int rep = 0; rep < 4; ++rep) rb[rep] = *(const float4*)bptr[rep];

  for (int kt = 0; kt < HID / 16; ++kt) {
    // commit staged regs to LDS
    As[ka + 0][rowA] = ra.x; As[ka + 1][rowA] = ra.y;
    As[ka + 2][rowA] = ra.z; As[ka + 3][rowA] = ra.w;
#pragma unroll
    for (int rep = 0; rep < 4; ++rep) {
      Bs[bs_s[rep]][bs_kc[rep] + 0][bs_jj[rep]] = rb[rep].x;
      Bs[bs_s[rep]][bs_kc[rep] + 1][bs_jj[rep]] = rb[rep].y;
      Bs[bs_s[rep]][bs_kc[rep] + 2][bs_jj[rep]] = rb[rep].z;
      Bs[bs_s[rep]][bs_kc[rep] + 3][bs_jj[rep]] = rb[rep].w;
    }
    __syncthreads();
    if (kt + 1 < HID / 16) {  // prefetch next K-slab while computing this one
      ra = *(const float4*)(aptr + (kt + 1) * 16);
#pragma unroll
      for (int rep = 0; rep < 4; ++rep)
        rb[rep] = *(const float4*)(bptr[rep] + (kt + 1) * 16);
    }
#pragma unroll
    for (int k = 0; k < 16; ++k) {
      float4 a = *(const float4*)&As[k][ty << 2];
      float af[4] = {a.x, a.y, a.z, a.w};
#pragma unroll
      for (int s = 0; s < 4; ++s) {
        float4 b = *(const float4*)&Bs[s][k][tx << 2];
        float bf[4] = {b.x, b.y, b.z, b.w};
#pragma unroll
        for (int i = 0; i < 4; ++i)
#pragma unroll
          for (int j = 0; j < 4; ++j) acc[s][i][j] += af[i] * bf[j];
      }
    }
    __syncthreads();
  }

  // epilogue: gates -> (c,h)
  const int m0 = mb * 64 + (ty << 2);
  const int nbase = nb * 64 + (tx << 2);
#pragma unroll
  for (int i = 0; i < 4; ++i) {
    const int m = m0 + i;
    const int t = tok[m];
    const float* Ero = E + (size_t)t * G4 + nbase;
    float4 ei = *(const float4*)(Ero + 0 * HID);
    float4 ef = *(const float4*)(Ero + 1 * HID);
    float4 eg = *(const float4*)(Ero + 2 * HID);
    float4 eo = *(const float4*)(Ero + 3 * HID);
    float* cp = c + (size_t)m * HID + nbase;
    float* hp = h_out + (size_t)m * HID + nbase;
    float4 cv = *(const float4*)cp;
    float4 cn, hn;
    float eiv[4] = {ei.x, ei.y, ei.z, ei.w};
    float efv[4] = {ef.x, ef.y, ef.z, ef.w};
    float egv[4] = {eg.x, eg.y, eg.z, eg.w};
    float eov[4] = {eo.x, eo.y, eo.z, eo.w};
    float cvv[4] = {cv.x, cv.y, cv.z, cv.w};
    float cnv[4], hnv[4];
#pragma unroll
    for (int j = 0; j < 4; ++j) {
      float gi = acc[0][i][j] + eiv[j];
      float gf = acc[1][i][j] + efv[j];
      float gg = acc[2][i][j] + egv[j];
      float go = acc[3][i][j] + eov[j];
      float si = 1.f / (1.f + expf(-gi));
      float sf = 1.f / (1.f + expf(-gf));
      float so = 1.f / (1.f + expf(-go));
      float nc = sf * cvv[j] + si * tanhf(gg);
      cnv[j] = nc;
      hnv[j] = so * tanhf(nc);
    }
    cn.x = cnv[0]; cn.y = cnv[1]; cn.z = cnv[2]; cn.w = cnv[3];
    hn.x = hnv[0]; hn.y = hnv[1]; hn.z = hnv[2]; hn.w = hnv[3];
    *(float4*)cp = cn;
    *(float4*)hp = hn;
  }
}

// ---------------- logits + softmax + categorical sample ----------------
// one wave (64 threads) per batch row; thread o owns output category o.
__global__ __launch_bounds__(64) void logits_kernel(
    const float* __restrict__ h,      // [B][HID]
    const float* __restrict__ W_lin,  // [64][512]
    const float* __restrict__ b_lin,  // [64]
    float* __restrict__ out,          // [B][STEPS][64]
    int* __restrict__ tok,            // [B]
    int step)
{
  const int b = blockIdx.x;
  const int o = threadIdx.x;
  __shared__ float hs[HID];
  {
    const float4* src = (const float4*)(h + (size_t)b * HID);
    float4 v0 = src[o * 2], v1 = src[o * 2 + 1];
    *(float4*)&hs[o * 8] = v0;
    *(float4*)&hs[o * 8 + 4] = v1;
  }
  __syncthreads();

  float acc = b_lin[o];
  const float* w = W_lin + (size_t)o * HID;
#pragma unroll 8
  for (int k = 0; k < HID; k += 4) {
    float4 wv = *(const float4*)(w + k);
    acc += wv.x * hs[k] + wv.y * hs[k + 1] + wv.z * hs[k + 2] + wv.w * hs[k + 3];
  }
  const float logit = acc;

  // softmax (stable)
  float m = logit;
#pragma unroll
  for (int d = 32; d; d >>= 1) m = fmaxf(m, __shfl_xor(m, d));
  float e = expf(logit - m);
  float ssum = e;
#pragma unroll
  for (int d = 32; d; d >>= 1) ssum += __shfl_xor(ssum, d);
  out[((size_t)b * STEPS + step) * NOUT + o] = e / ssum;

  // gumbel-max sample, JAX threefry partitionable semantics
  uint32_t s0, s1;
  tf2x32(0u, 42u, 0u, (uint32_t)step, s0, s1);  // split(key(42))[step]
  uint32_t r0, r1;
  const uint32_t idx = (uint32_t)(b * NOUT + o);
  tf2x32(s0, s1, 0u, idx, r0, r1);
  const uint32_t bits = r0 ^ r1;
  float u = __uint_as_float((bits >> 9) | 0x3f800000u) - 1.0f;
  u = fmaxf(u, 1.17549435e-38f);
  const float gmb = -logf(-logf(u));

  float v = logit + gmb;
  int bi = o;
#pragma unroll
  for (int d = 32; d; d >>= 1) {
    float ov = __shfl_xor(v, d);
    int oi = __shfl_xor(bi, d);
    if (ov > v || (ov == v && oi < bi)) { v = ov; bi = oi; }
  }
  if (o == 0) tok[b] = bi;
}

// ---------------- host ----------------
extern "C" void kernel_launch(void* const* d_in, const int* in_sizes, int n_in,
                              void* d_out, int out_size, void* d_ws, size_t ws_size,
                              hipStream_t stream) {
  const int*   x     = (const int*)d_in[0];
  const float* emb   = (const float*)d_in[1];
  const float* W_ih  = (const float*)d_in[2];
  const float* W_hh  = (const float*)d_in[3];
  const float* b_ih  = (const float*)d_in[4];
  const float* b_hh  = (const float*)d_in[5];
  const float* W_lin = (const float*)d_in[6];
  const float* b_lin = (const float*)d_in[7];
  float* out = (float*)d_out;

  float* E  = (float*)d_ws;          // 64*2048
  float* h0 = E + 64 * G4;           // B*HID
  float* h1 = h0 + (size_t)B_SZ * HID;
  float* c  = h1 + (size_t)B_SZ * HID;
  int*  tok = (int*)(c + (size_t)B_SZ * HID);

  hipMemsetAsync(h0, 0, (size_t)B_SZ * HID * sizeof(float), stream);
  hipMemsetAsync(c,  0, (size_t)B_SZ * HID * sizeof(float), stream);

  eproj_kernel<<<64, 256, 0, stream>>>(emb, W_ih, b_ih, b_hh, E);

  const int* cur_tok = x;
  float* hprev = h0;
  float* hnext = h1;
  for (int t = 0; t < STEPS; ++t) {
    dim3 grid(8, 64);
    lstm_step_kernel<<<grid, 256, 0, stream>>>(hprev, c, hnext, W_hh, E, cur_tok);
    logits_kernel<<<B_SZ, 64, 0, stream>>>(hnext, W_lin, b_lin, out, tok, t);
    cur_tok = tok;
    float* tmp = hprev; hprev = hnext; hnext = tmp;
  }
}